// Round 3
// baseline (592.348 us; speedup 1.0000x reference)
//
#include <hip/hip_runtime.h>

// VQ-VAE VectorQuantizer: B=32, C=D=64, H=W=64, K=512
// d_in[0]: inputs  [32,64,64,64] f32 (NCHW, C = embedding dim)
// d_in[1]: embedding [512,64] f32
// d_out: [loss(1) | out(32*64*64*64) | indices(32*4096)] all read as f32
//
// Numerics (verified passing in R2): comparator recomputes in numpy fp32:
//   d_k = (x2 - 2*xe_k + e2_k)/64, argmin (first min). We replicate numpy's
//   rounding: pairwise-8 sums for x2/e2 (squares rounded BEFORE add), then
//   d = fl(fl(x2 - 2*xe) + e2). /64 dropped (argmin-invariant).
//
// R3 change: split each position's 512 codes across 4 waves (wave = code
// quarter -> emb reads stay wave-uniform s_loads). 2048 blocks -> 16+ waves/CU
// (was 8) to hide the per-k s_load latency that left VALUBusy at 30%.

#define KCODE 512
#define EMB   64
#define HWSZ  4096          // H*W
#define BATCH 32
#define NPOS  (BATCH * HWSZ) // 131072
#define QUART 4              // waves (code quarters) per position
#define KPQ   (KCODE / QUART) // 128 codes per thread
#define POSB  64             // positions per block

// numpy pairwise_sum leaf for n=64 (unrolled-by-8), squares NOT fused.
__device__ __forceinline__ float np_sumsq64(const float* a) {
    #pragma clang fp contract(off)
    {
        float r0 = a[0] * a[0], r1 = a[1] * a[1], r2 = a[2] * a[2], r3 = a[3] * a[3];
        float r4 = a[4] * a[4], r5 = a[5] * a[5], r6 = a[6] * a[6], r7 = a[7] * a[7];
        for (int i = 8; i < 64; i += 8) {
            r0 += a[i + 0] * a[i + 0];
            r1 += a[i + 1] * a[i + 1];
            r2 += a[i + 2] * a[i + 2];
            r3 += a[i + 3] * a[i + 3];
            r4 += a[i + 4] * a[i + 4];
            r5 += a[i + 5] * a[i + 5];
            r6 += a[i + 6] * a[i + 6];
            r7 += a[i + 7] * a[i + 7];
        }
        return ((r0 + r1) + (r2 + r3)) + ((r4 + r5) + (r6 + r7));
    }
}

// ws (float view): ws[0] = loss accumulator; ws[8..8+511] = ||e_k||^2 (np order)
__global__ void vq_precompute(const float* __restrict__ emb, float* __restrict__ ws) {
    int k = blockIdx.x * blockDim.x + threadIdx.x;
    if (k == 0) ws[0] = 0.0f;           // zero loss accumulator (d_ws is poisoned)
    if (k < KCODE) {
        ws[8 + k] = np_sumsq64(emb + k * EMB);
    }
}

__global__ __launch_bounds__(256) void vq_main(
        const float* __restrict__ in,      // [32,64,4096]
        const float* __restrict__ emb,     // [512,64]
        const float* __restrict__ e2,      // ws+8, [512]
        float* __restrict__ loss_accum,    // ws+0
        float* __restrict__ out_q,         // d_out+1, [32,64,4096]
        float* __restrict__ out_idx) {     // d_out+1+NPOS*EMB, [NPOS]
    const int pos = threadIdx.x & 63;                // position within block
    const int q   = threadIdx.x >> 6;                // wave id = code quarter
    const int n   = blockIdx.x * POSB + pos;         // global position id
    const int b   = n >> 12;                         // / 4096
    const int hw  = n & (HWSZ - 1);

    // Load this position's 64-dim vector (stride HWSZ between components;
    // coalesced across lanes since lanes have consecutive hw).
    const float* xp = in + (size_t)b * (EMB * HWSZ) + hw;
    float x[EMB];
    #pragma unroll
    for (int c = 0; c < EMB; ++c) x[c] = xp[(size_t)c * HWSZ];

    // x2 with numpy's exact summation pattern (redundant per quarter; cheap).
    const float x2 = np_sumsq64(x);

    // argmin over this thread's 128 codes; k wave-uniform -> emb s_loads.
    const int k0 = q * KPQ;
    int   best  = k0;
    float bestD = 3.4e38f;
    #pragma unroll 2
    for (int k = k0; k < k0 + KPQ; ++k) {
        const float* ek = emb + k * EMB;
        float t0 = 0.f, t1 = 0.f, t2 = 0.f, t3 = 0.f;
        #pragma unroll
        for (int c = 0; c < EMB; c += 4) {
            t0 = fmaf(x[c + 0], ek[c + 0], t0);
            t1 = fmaf(x[c + 1], ek[c + 1], t1);
            t2 = fmaf(x[c + 2], ek[c + 2], t2);
            t3 = fmaf(x[c + 3], ek[c + 3], t3);
        }
        float xe  = (t0 + t1) + (t2 + t3);
        float tmp = x2 - 2.0f * xe;      // fl(x2 - 2*xe): the ulp(64) quantizer
        float d   = tmp + e2[k];         // fl(tmp + e2)
        if (d < bestD) { bestD = d; best = k; }   // strict <: first min kept
    }

    // Cross-quarter argmin (ascending quarter + strict < == global first-min).
    __shared__ float sD[QUART][POSB];
    __shared__ int   sK[QUART][POSB];
    __shared__ float red[QUART];
    sD[q][pos] = bestD;
    sK[q][pos] = best;
    __syncthreads();
    if (threadIdx.x < POSB) {
        float dmin = sD[0][pos];
        int   kmin = sK[0][pos];
        #pragma unroll
        for (int qq = 1; qq < QUART; ++qq) {
            float dq = sD[qq][pos];
            if (dq < dmin) { dmin = dq; kmin = sK[qq][pos]; }
        }
        sK[0][pos] = kmin;
        out_idx[n] = (float)kmin;
    }
    __syncthreads();

    // Phase 3: each thread writes 16 components of its position, accumulating
    // the (q - x)^2 loss partial. x re-loaded from global (L1-hot) to avoid
    // runtime-indexing the x[] register array.
    const int kk = sK[0][pos];
    const int c0 = q * 16;
    const float4* er = (const float4*)(emb + (size_t)kk * EMB + c0);
    const float*  xr = xp + (size_t)c0 * HWSZ;
    float* op = out_q + (size_t)b * (EMB * HWSZ) + (size_t)c0 * HWSZ + hw;
    float s = 0.0f;
    #pragma unroll
    for (int i4 = 0; i4 < 4; ++i4) {
        float4 v = er[i4];
        float xa = xr[(size_t)(i4 * 4 + 0) * HWSZ];
        float xb = xr[(size_t)(i4 * 4 + 1) * HWSZ];
        float xc = xr[(size_t)(i4 * 4 + 2) * HWSZ];
        float xd = xr[(size_t)(i4 * 4 + 3) * HWSZ];
        float d0 = v.x - xa, d1 = v.y - xb, d2 = v.z - xc, d3 = v.w - xd;
        s = fmaf(d0, d0, s); s = fmaf(d1, d1, s);
        s = fmaf(d2, d2, s); s = fmaf(d3, d3, s);
        op[(size_t)(i4 * 4 + 0) * HWSZ] = v.x;
        op[(size_t)(i4 * 4 + 1) * HWSZ] = v.y;
        op[(size_t)(i4 * 4 + 2) * HWSZ] = v.z;
        op[(size_t)(i4 * 4 + 3) * HWSZ] = v.w;
    }

    // Block-level loss reduction: wave shuffle -> LDS -> one atomic per block.
    #pragma unroll
    for (int off = 32; off > 0; off >>= 1)
        s += __shfl_down(s, off, 64);
    const int lane = threadIdx.x & 63;
    if (lane == 0) red[q] = s;
    __syncthreads();
    if (threadIdx.x == 0) {
        float bs = (red[0] + red[1]) + (red[2] + red[3]);
        atomicAdd(loss_accum, bs);
    }
}

__global__ void vq_finalize(const float* __restrict__ loss_accum,
                            float* __restrict__ out0) {
    // loss = q_latent + 0.25*e_latent = 1.25 * mean((q - x)^2)
    out0[0] = 1.25f * loss_accum[0] * (1.0f / ((float)NPOS * (float)EMB));
}

extern "C" void kernel_launch(void* const* d_in, const int* in_sizes, int n_in,
                              void* d_out, int out_size, void* d_ws, size_t ws_size,
                              hipStream_t stream) {
    const float* in  = (const float*)d_in[0];
    const float* emb = (const float*)d_in[1];
    float* ws   = (float*)d_ws;
    float* out  = (float*)d_out;

    float* loss_accum = ws;            // ws[0]
    float* e2         = ws + 8;        // ws[8..519]
    float* out_loss   = out;           // [1]
    float* out_q      = out + 1;       // [NPOS*EMB]
    float* out_idx    = out + 1 + (size_t)NPOS * EMB;  // [NPOS]

    vq_precompute<<<2, 256, 0, stream>>>(emb, ws);
    vq_main<<<NPOS / POSB, 256, 0, stream>>>(in, emb, e2, loss_accum, out_q, out_idx);
    vq_finalize<<<1, 1, 0, stream>>>(loss_accum, out_loss);
}

// Round 4
// 373.864 us; speedup vs baseline: 1.5844x; 1.5844x over previous
//
#include <hip/hip_runtime.h>

// VQ-VAE VectorQuantizer: B=32, C=D=64, H=W=64, K=512
// d_in[0]: inputs  [32,64,64,64] f32 (NCHW, C = embedding dim)
// d_in[1]: embedding [512,64] f32
// d_out: [loss(1) | out(32*64*64*64) | indices(32*4096)] all read as f32
//
// Numerics (verified passing in R2): comparator recomputes in numpy fp32:
//   d_k = (x2 - 2*xe_k + e2_k)/64, argmin (first min). We replicate numpy's
//   rounding: pairwise-8 sums for x2/e2 (squares rounded BEFORE add), then
//   d = fl(fl(x2 - 2*xe) + e2). /64 dropped (argmin-invariant). All fp ops on
//   the argmin path are order-identical to the R2-passing kernel.
//
// R4: R2/R3 had VGPR_Count=64/60 -> occupancy-driven RA refused to keep x[64]
// resident and re-issued 64 global loads per k (the real 30%-VALUBusy cause).
// Fix: __launch_bounds__(256,2) (grid only gives 2 waves/SIMD anyway) so x
// stays in VGPRs, and emb comes from LDS chunks (uniform ds_read_b128
// broadcast) instead of s_load/VMEM. k-loop issues zero VMEM.

#define KCODE 512
#define EMB   64
#define HWSZ  4096          // H*W
#define BATCH 32
#define NPOS  (BATCH * HWSZ) // 131072
#define CHUNK 64             // codes staged per LDS chunk (16 KB)
#define NCHUNK (KCODE / CHUNK)

// numpy pairwise_sum leaf for n=64 (unrolled-by-8), squares NOT fused.
// Fully unrolled so the caller's array is never dynamically indexed.
__device__ __forceinline__ float np_sumsq64(const float* a) {
    #pragma clang fp contract(off)
    {
        float r0 = a[0] * a[0], r1 = a[1] * a[1], r2 = a[2] * a[2], r3 = a[3] * a[3];
        float r4 = a[4] * a[4], r5 = a[5] * a[5], r6 = a[6] * a[6], r7 = a[7] * a[7];
        #pragma unroll
        for (int i = 8; i < 64; i += 8) {
            r0 += a[i + 0] * a[i + 0];
            r1 += a[i + 1] * a[i + 1];
            r2 += a[i + 2] * a[i + 2];
            r3 += a[i + 3] * a[i + 3];
            r4 += a[i + 4] * a[i + 4];
            r5 += a[i + 5] * a[i + 5];
            r6 += a[i + 6] * a[i + 6];
            r7 += a[i + 7] * a[i + 7];
        }
        return ((r0 + r1) + (r2 + r3)) + ((r4 + r5) + (r6 + r7));
    }
}

// ws (float view): ws[0] = loss accumulator; ws[8..8+511] = ||e_k||^2 (np order)
__global__ void vq_precompute(const float* __restrict__ emb, float* __restrict__ ws) {
    int k = blockIdx.x * blockDim.x + threadIdx.x;
    if (k == 0) ws[0] = 0.0f;           // zero loss accumulator (d_ws is poisoned)
    if (k < KCODE) {
        ws[8 + k] = np_sumsq64(emb + k * EMB);
    }
}

__global__ __launch_bounds__(256, 2) void vq_main(
        const float* __restrict__ in,      // [32,64,4096]
        const float* __restrict__ emb,     // [512,64]
        const float* __restrict__ e2,      // ws+8, [512]
        float* __restrict__ loss_accum,    // ws+0
        float* __restrict__ out_q,         // d_out+1, [32,64,4096]
        float* __restrict__ out_idx) {     // d_out+1+NPOS*EMB, [NPOS]
    const int tid = threadIdx.x;
    const int n   = blockIdx.x * 256 + tid;          // position id
    const int b   = n >> 12;                         // / 4096
    const int hw  = n & (HWSZ - 1);

    __shared__ float se[CHUNK * EMB];   // 16 KB: current 64-code chunk
    __shared__ float se2[KCODE];        // 2 KB: ||e_k||^2
    __shared__ float red[4];

    // Stage e2 once.
    se2[tid]       = e2[tid];
    se2[tid + 256] = e2[tid + 256];

    // Load this position's 64-dim vector into REGISTERS (stride HWSZ between
    // components; coalesced across lanes since lanes have consecutive hw).
    const float* xp = in + (size_t)b * (EMB * HWSZ) + hw;
    float x[EMB];
    #pragma unroll
    for (int c = 0; c < EMB; ++c) x[c] = xp[(size_t)c * HWSZ];

    // x2 with numpy's exact summation pattern.
    const float x2 = np_sumsq64(x);

    // argmin over all 512 codes, embedding rows served from LDS.
    int   best  = 0;
    float bestD = 3.4e38f;
    for (int ch = 0; ch < NCHUNK; ++ch) {
        __syncthreads();   // previous chunk's readers done
        // Cooperative stage: 16 KB = 4 rounds x 256 threads x 16 B, coalesced.
        const float* gsrc = emb + (size_t)ch * (CHUNK * EMB);
        #pragma unroll
        for (int r = 0; r < 4; ++r) {
            *(float4*)(se + r * 1024 + tid * 4) =
                *(const float4*)(gsrc + r * 1024 + tid * 4);
        }
        __syncthreads();

        #pragma unroll 2
        for (int kk = 0; kk < CHUNK; ++kk) {
            const int k = ch * CHUNK + kk;
            const float* ek = se + kk * EMB;   // wave-uniform -> LDS broadcast
            float t0 = 0.f, t1 = 0.f, t2 = 0.f, t3 = 0.f;
            #pragma unroll
            for (int c = 0; c < EMB; c += 4) {
                t0 = fmaf(x[c + 0], ek[c + 0], t0);
                t1 = fmaf(x[c + 1], ek[c + 1], t1);
                t2 = fmaf(x[c + 2], ek[c + 2], t2);
                t3 = fmaf(x[c + 3], ek[c + 3], t3);
            }
            float xe  = (t0 + t1) + (t2 + t3);
            float tmp = x2 - 2.0f * xe;    // fl(x2 - 2*xe): the ulp(64) quantizer
            float d   = tmp + se2[k];      // fl(tmp + e2)
            if (d < bestD) { bestD = d; best = k; }   // strict <: first min kept
        }
    }

    // Quantized output (forward value of straight-through = embedding row),
    // plus per-thread sum of (q - x)^2 for the loss.
    const float4* qk = (const float4*)(emb + (size_t)best * EMB);
    float* op = out_q + (size_t)b * (EMB * HWSZ) + hw;
    float s = 0.0f;
    #pragma unroll
    for (int c4 = 0; c4 < EMB / 4; ++c4) {
        float4 v = qk[c4];
        float d0 = v.x - x[c4 * 4 + 0];
        float d1 = v.y - x[c4 * 4 + 1];
        float d2 = v.z - x[c4 * 4 + 2];
        float d3 = v.w - x[c4 * 4 + 3];
        s = fmaf(d0, d0, s); s = fmaf(d1, d1, s);
        s = fmaf(d2, d2, s); s = fmaf(d3, d3, s);
        op[(size_t)(c4 * 4 + 0) * HWSZ] = v.x;
        op[(size_t)(c4 * 4 + 1) * HWSZ] = v.y;
        op[(size_t)(c4 * 4 + 2) * HWSZ] = v.z;
        op[(size_t)(c4 * 4 + 3) * HWSZ] = v.w;
    }
    out_idx[n] = (float)best;

    // Block-level loss reduction: wave shuffle -> LDS -> one atomic per block.
    #pragma unroll
    for (int off = 32; off > 0; off >>= 1)
        s += __shfl_down(s, off, 64);
    const int wave = tid >> 6;
    const int lane = tid & 63;
    if (lane == 0) red[wave] = s;
    __syncthreads();
    if (tid == 0) {
        float bs = (red[0] + red[1]) + (red[2] + red[3]);
        atomicAdd(loss_accum, bs);
    }
}

__global__ void vq_finalize(const float* __restrict__ loss_accum,
                            float* __restrict__ out0) {
    // loss = q_latent + 0.25*e_latent = 1.25 * mean((q - x)^2)
    out0[0] = 1.25f * loss_accum[0] * (1.0f / ((float)NPOS * (float)EMB));
}

extern "C" void kernel_launch(void* const* d_in, const int* in_sizes, int n_in,
                              void* d_out, int out_size, void* d_ws, size_t ws_size,
                              hipStream_t stream) {
    const float* in  = (const float*)d_in[0];
    const float* emb = (const float*)d_in[1];
    float* ws   = (float*)d_ws;
    float* out  = (float*)d_out;

    float* loss_accum = ws;            // ws[0]
    float* e2         = ws + 8;        // ws[8..519]
    float* out_loss   = out;           // [1]
    float* out_q      = out + 1;       // [NPOS*EMB]
    float* out_idx    = out + 1 + (size_t)NPOS * EMB;  // [NPOS]

    vq_precompute<<<2, 256, 0, stream>>>(emb, ws);
    vq_main<<<NPOS / 256, 256, 0, stream>>>(in, emb, e2, loss_accum, out_q, out_idx);
    vq_finalize<<<1, 1, 0, stream>>>(loss_accum, out_loss);
}

// Round 5
// 329.177 us; speedup vs baseline: 1.7995x; 1.1358x over previous
//
#include <hip/hip_runtime.h>

// VQ-VAE VectorQuantizer: B=32, C=D=64, H=W=64, K=512
// d_in[0]: inputs  [32,64,64,64] f32 (NCHW, C = embedding dim)
// d_in[1]: embedding [512,64] f32
// d_out: [loss(1) | out(32*64*64*64) | indices(32*4096)] all read as f32
//
// Numerics (verified passing in R2): comparator recomputes in numpy fp32:
//   d_k = (x2 - 2*xe_k + e2_k)/64, argmin (first min). We replicate numpy's
//   rounding: pairwise-8 sums for x2/e2 (squares rounded BEFORE add), then
//   d = fl(fl(x2 - 2*xe) + e2). /64 dropped (argmin-invariant). All fp ops on
//   the argmin path are order-identical to the R2-passing kernel.
//
// R5: combine the two halves that each round proved separately.
//   R2 (VGPR=64, SGPR=96): emb served via wave-uniform s_load -> SGPR operand
//     of v_fma (zero per-lane bandwidth), but x[64] NOT register-resident ->
//     per-k x reloads -> 30% VALUBusy, 237 us.
//   R4 (VGPR=72): x resident, but emb via LDS ds_read_b128 -> LDS return path
//     delivers 1KB/instr/wave; 16 reads x ~12cyc x 512k x 8 waves/CU ~= 330 us
//     == measured. LDS broadcast saves conflicts, not register-write BW.
//   R5 = resident x (__launch_bounds__(256,2); grid gives only 2 waves/SIMD
//   anyway) + emb/e2 read directly from global with wave-uniform addresses
//   (compiler -> s_load, as in R2). k-loop: 64 v_fma + 4 s_load_dwordx16,
//   FMA-bound at ~55 us/SIMD-pair.

#define KCODE 512
#define EMB   64
#define HWSZ  4096          // H*W
#define BATCH 32
#define NPOS  (BATCH * HWSZ) // 131072

// numpy pairwise_sum leaf for n=64 (unrolled-by-8), squares NOT fused.
// Fully unrolled so the caller's array is never dynamically indexed.
__device__ __forceinline__ float np_sumsq64(const float* a) {
    #pragma clang fp contract(off)
    {
        float r0 = a[0] * a[0], r1 = a[1] * a[1], r2 = a[2] * a[2], r3 = a[3] * a[3];
        float r4 = a[4] * a[4], r5 = a[5] * a[5], r6 = a[6] * a[6], r7 = a[7] * a[7];
        #pragma unroll
        for (int i = 8; i < 64; i += 8) {
            r0 += a[i + 0] * a[i + 0];
            r1 += a[i + 1] * a[i + 1];
            r2 += a[i + 2] * a[i + 2];
            r3 += a[i + 3] * a[i + 3];
            r4 += a[i + 4] * a[i + 4];
            r5 += a[i + 5] * a[i + 5];
            r6 += a[i + 6] * a[i + 6];
            r7 += a[i + 7] * a[i + 7];
        }
        return ((r0 + r1) + (r2 + r3)) + ((r4 + r5) + (r6 + r7));
    }
}

// ws (float view): ws[0] = loss accumulator; ws[8..8+511] = ||e_k||^2 (np order)
__global__ void vq_precompute(const float* __restrict__ emb, float* __restrict__ ws) {
    int k = blockIdx.x * blockDim.x + threadIdx.x;
    if (k == 0) ws[0] = 0.0f;           // zero loss accumulator (d_ws is poisoned)
    if (k < KCODE) {
        ws[8 + k] = np_sumsq64(emb + k * EMB);
    }
}

__global__ __launch_bounds__(256, 2) void vq_main(
        const float* __restrict__ in,      // [32,64,4096]
        const float* __restrict__ emb,     // [512,64]
        const float* __restrict__ e2,      // ws+8, [512]
        float* __restrict__ loss_accum,    // ws+0
        float* __restrict__ out_q,         // d_out+1, [32,64,4096]
        float* __restrict__ out_idx) {     // d_out+1+NPOS*EMB, [NPOS]
    const int tid = threadIdx.x;
    const int n   = blockIdx.x * 256 + tid;          // position id
    const int b   = n >> 12;                         // / 4096
    const int hw  = n & (HWSZ - 1);

    // Load this position's 64-dim vector into REGISTERS (stride HWSZ between
    // components; coalesced across lanes since lanes have consecutive hw).
    const float* xp = in + (size_t)b * (EMB * HWSZ) + hw;
    float x[EMB];
    #pragma unroll
    for (int c = 0; c < EMB; ++c) x[c] = xp[(size_t)c * HWSZ];

    // x2 with numpy's exact summation pattern.
    const float x2 = np_sumsq64(x);

    // argmin over all 512 codes. k is wave-uniform -> ek[c]/e2[k] addresses
    // are uniform -> compiler emits s_load; emb rides the scalar operand bus
    // (no per-lane bandwidth), x[] stays in VGPRs.
    int   best  = 0;
    float bestD = 3.4e38f;
    #pragma unroll 2
    for (int k = 0; k < KCODE; ++k) {
        const float* ek = emb + k * EMB;
        float t0 = 0.f, t1 = 0.f, t2 = 0.f, t3 = 0.f;
        #pragma unroll
        for (int c = 0; c < EMB; c += 4) {
            t0 = fmaf(x[c + 0], ek[c + 0], t0);
            t1 = fmaf(x[c + 1], ek[c + 1], t1);
            t2 = fmaf(x[c + 2], ek[c + 2], t2);
            t3 = fmaf(x[c + 3], ek[c + 3], t3);
        }
        float xe  = (t0 + t1) + (t2 + t3);
        float tmp = x2 - 2.0f * xe;      // fl(x2 - 2*xe): the ulp(64) quantizer
        float d   = tmp + e2[k];         // fl(tmp + e2)
        if (d < bestD) { bestD = d; best = k; }   // strict <: first min kept
    }

    // Quantized output (forward value of straight-through = embedding row),
    // plus per-thread sum of (q - x)^2 for the loss.
    const float4* qk = (const float4*)(emb + (size_t)best * EMB);
    float* op = out_q + (size_t)b * (EMB * HWSZ) + hw;
    float s = 0.0f;
    #pragma unroll
    for (int c4 = 0; c4 < EMB / 4; ++c4) {
        float4 v = qk[c4];
        float d0 = v.x - x[c4 * 4 + 0];
        float d1 = v.y - x[c4 * 4 + 1];
        float d2 = v.z - x[c4 * 4 + 2];
        float d3 = v.w - x[c4 * 4 + 3];
        s = fmaf(d0, d0, s); s = fmaf(d1, d1, s);
        s = fmaf(d2, d2, s); s = fmaf(d3, d3, s);
        op[(size_t)(c4 * 4 + 0) * HWSZ] = v.x;
        op[(size_t)(c4 * 4 + 1) * HWSZ] = v.y;
        op[(size_t)(c4 * 4 + 2) * HWSZ] = v.z;
        op[(size_t)(c4 * 4 + 3) * HWSZ] = v.w;
    }
    out_idx[n] = (float)best;

    // Block-level loss reduction: wave shuffle -> LDS -> one atomic per block.
    float ssum = s;
    #pragma unroll
    for (int off = 32; off > 0; off >>= 1)
        ssum += __shfl_down(ssum, off, 64);
    __shared__ float red[4];
    const int wave = tid >> 6;
    const int lane = tid & 63;
    if (lane == 0) red[wave] = ssum;
    __syncthreads();
    if (tid == 0) {
        float bs = (red[0] + red[1]) + (red[2] + red[3]);
        atomicAdd(loss_accum, bs);
    }
}

__global__ void vq_finalize(const float* __restrict__ loss_accum,
                            float* __restrict__ out0) {
    // loss = q_latent + 0.25*e_latent = 1.25 * mean((q - x)^2)
    out0[0] = 1.25f * loss_accum[0] * (1.0f / ((float)NPOS * (float)EMB));
}

extern "C" void kernel_launch(void* const* d_in, const int* in_sizes, int n_in,
                              void* d_out, int out_size, void* d_ws, size_t ws_size,
                              hipStream_t stream) {
    const float* in  = (const float*)d_in[0];
    const float* emb = (const float*)d_in[1];
    float* ws   = (float*)d_ws;
    float* out  = (float*)d_out;

    float* loss_accum = ws;            // ws[0]
    float* e2         = ws + 8;        // ws[8..519]
    float* out_loss   = out;           // [1]
    float* out_q      = out + 1;       // [NPOS*EMB]
    float* out_idx    = out + 1 + (size_t)NPOS * EMB;  // [NPOS]

    vq_precompute<<<2, 256, 0, stream>>>(emb, ws);
    vq_main<<<NPOS / 256, 256, 0, stream>>>(in, emb, e2, loss_accum, out_q, out_idx);
    vq_finalize<<<1, 1, 0, stream>>>(loss_accum, out_loss);
}